// Round 10
// baseline (70.574 us; speedup 1.0000x reference)
//
#include <hip/hip_runtime.h>
#include <math.h>

#define NB 512
#define TT 26
#define LL 64
#define HH 32
#define WW 128

typedef unsigned long long ull;

__device__ __forceinline__ float wave_sum(float v) {
#pragma unroll
  for (int o = 32; o > 0; o >>= 1) v += __shfl_xor(v, o, 64);
  return v;
}

template<int CTRL, int RM>
__device__ __forceinline__ float dpp_add(float x) {
  int y = __builtin_amdgcn_update_dpp(0, __float_as_int(x), CTRL, RM, 0xf, true);
  return x + __int_as_float(y);
}
// sum across 64 lanes via DPP (VALU pipe only); result valid in lane 63
__device__ __forceinline__ float wave_red63(float x) {
  x = dpp_add<0x111, 0xf>(x);   // row_shr:1
  x = dpp_add<0x112, 0xf>(x);   // row_shr:2
  x = dpp_add<0x114, 0xf>(x);   // row_shr:4
  x = dpp_add<0x118, 0xf>(x);   // row_shr:8
  x = dpp_add<0x142, 0xa>(x);   // row_bcast15 -> rows 1,3
  x = dpp_add<0x143, 0xc>(x);   // row_bcast31 -> rows 2,3; lane63 = total
  return x;
}

// ================= Mega kernel: one block per sample b, 1024 threads =================
__global__ __launch_bounds__(1024) void k_mega(
    const float* __restrict__ masks, const float* __restrict__ bf,
    const float* __restrict__ seq, const float* __restrict__ cm,
    const float* __restrict__ cl, const int* __restrict__ length,
    const float* __restrict__ alpha_p,
    float* __restrict__ out_mask, float* __restrict__ out_smid,
    float* __restrict__ out_slow,
    float* __restrict__ seg_part, float* __restrict__ cor_part,
    float* __restrict__ irr_part, float* __restrict__ celm_part,
    float* __restrict__ cell_part,
    float* __restrict__ inter_mid, float* __restrict__ m1s_mid, float* __restrict__ m2s_mid,
    float* __restrict__ inter_low, float* __restrict__ m1s_low, float* __restrict__ m2s_low)
{
  int b = blockIdx.x;
  int tid = threadIdx.x;
  int lane = tid & 63, wv = tid >> 6;

  __shared__ float att[LL * TT];          // [l][t]
  __shared__ float wsA_lds[WW];
  __shared__ ull s_bits[TT];              // amid bitmasks (64 cols)
  __shared__ unsigned s_alow[TT];         // alow bitmasks (32 cols)
  __shared__ unsigned s_cols_mid[64];
  __shared__ unsigned s_cols_low[32];
  __shared__ ull fmsk_lds[64];            // fore mask, 32 rows x 2 words
  __shared__ ull s_fmrow[16];             // mid fm row masks
  __shared__ unsigned fmrow32[8];         // low fm row masks
  __shared__ float s_red_in[16][TT], s_red_m1[16][TT];
  __shared__ float s_ce[16];
  __shared__ float ps[16], pc[16];
  __shared__ float wpart[2];

  int n = length[b] - 1;
  float alpha = alpha_p[0];

  // ---- load attention [64][26] ----
  const float* sb = seq + (size_t)b * (LL * TT);
  for (int i = tid; i < LL * TT; i += 1024) att[i] = sb[i];
  __syncthreads();   // B0

  // ---- phase 1: interp sums + bitmasks (threads 0..127) ----
  if (tid < 128) {
    int w = tid;
    int k = w >> 1;
    int i0, i1; float c0, c1;
    if ((w & 1) == 0) {
      if (k == 0) { i0 = 0; i1 = 0; c0 = 1.f; c1 = 0.f; }
      else        { i0 = k - 1; i1 = k; c0 = 0.25f; c1 = 0.75f; }
    } else {
      if (k == 63) { i0 = 63; i1 = 63; c0 = 1.f; c1 = 0.f; }
      else         { i0 = k; i1 = k + 1; c0 = 0.75f; c1 = 0.25f; }
    }
    float S = 0.f, S2 = 0.f, A = 0.f;
    for (int t = 0; t < n; ++t) {
      float v = c0 * att[i0 * TT + t] + c1 * att[i1 * TT + t];
      float s = v * v;
      S += s; S2 += s * s;
      A += 1.f / (1.f + __expf(-70.f * (v - 0.1f)));
    }
    wsA_lds[w] = A;
    float c = S * S - S2;
    c = wave_sum(c);
    if (lane == 0) wpart[wv] = c;
  }
  if (tid < 64) {
    int x = tid;                       // middle: identity resize, 64 cols
    for (int t = 0; t < TT; ++t) {
      bool pred = (t < n) && (att[x * TT + t] > alpha);
      ull m = __ballot(pred);
      if (x == 0) s_bits[t] = m;
    }
  } else if (tid < 128) {
    int x = tid - 64;                  // low: pairwise mean, 32 cols
    for (int t = 0; t < TT; ++t) {
      bool pred = (x < 32) && (t < n) &&
                  (0.5f * (att[(2 * x) * TT + t] + att[(2 * x + 1) * TT + t]) > alpha);
      ull m = __ballot(pred);
      if (x == 0) s_alow[t] = (unsigned)m;
    }
  }
  __syncthreads();   // B1
  if (tid == 0) irr_part[b] = 0.5f * (wpart[0] + wpart[1]) / (float)n;

  // ---- column bitmasks (t-bits per column) ----
  if (tid < 64) {
    unsigned cb = 0;
#pragma unroll
    for (int t = 0; t < TT; ++t) cb |= (unsigned)((s_bits[t] >> tid) & 1ULL) << t;
    s_cols_mid[tid] = cb;
  } else if (tid < 96) {
    int xc = tid - 64;
    unsigned cb = 0;
#pragma unroll
    for (int t = 0; t < TT; ++t) cb |= ((s_alow[t] >> xc) & 1u) << t;
    s_cols_low[xc] = cb;
  }

  // ---- phase 2: seg CE + correct CE + fore mask (all threads, 4 px each) ----
  {
    const float* mb = masks + (size_t)b * 4096;
    const float* fb = bf + (size_t)b * 8192;
    float A = wsA_lds[tid & 127];
    float cs = fminf(fmaxf(A, 0.f), 1.f);
    float ce_fore = log1pf(__expf(1.f - 2.f * cs));
    float seg_acc = 0.f, cor_acc = 0.f;
    for (int k = 0; k < 4; ++k) {
      int px = k * 1024 + tid;
      float m = mb[px];
      float b0 = fb[px];
      float b1 = fb[4096 + px];
      float mx = fmaxf(b0, b1);
      float e0 = __expf(b0 - mx), e1 = __expf(b1 - mx);
      float inv = 1.f / (e0 + e1);
      float p0 = e0 * inv, p1 = e1 * inv;
      float pm = fmaxf(p0, p1);
      float lse = pm + log1pf(__expf(-fabsf(p1 - p0)));
      seg_acc += lse - ((m > 0.5f) ? p1 : p0);
      bool fore = b1 > b0;
      cor_acc += fore ? ce_fore : 0.313261687518222834f;
      ull fbm = __ballot(fore);
      if (lane == 0) fmsk_lds[k * 16 + wv] = fbm;
    }
    seg_acc = wave_red63(seg_acc);
    cor_acc = wave_red63(cor_acc);
    if (lane == 63) { ps[wv] = seg_acc; pc[wv] = cor_acc; }
  }
  __syncthreads();   // B2
  if (tid == 0) {
    float s = 0.f, c = 0.f;
#pragma unroll
    for (int i = 0; i < 16; ++i) { s += ps[i]; c += pc[i]; }
    seg_part[b] = s;
    cor_part[b] = c;
  }

  // ---- mid branch: 1024 px, 1 px/thread; wave == row y ----
  {
    int y = wv;                  // 0..15
    int x = tid & 63;
    int word = x >> 5;
    int p = (x & 31) * 2;
    ull r0 = fmsk_lds[4 * y + word];
    ull r1 = fmsk_lds[4 * y + 2 + word];
    int cnt = (int)((r0 >> p) & 1) + (int)((r0 >> (p + 1)) & 1)
            + (int)((r1 >> p) & 1) + (int)((r1 >> (p + 1)) & 1);
    bool fm = cnt >= 2;
    unsigned cbk = s_cols_mid[x];
    int lab = (fm && cbk) ? __ffs((int)cbk) : 0;
    if (!fm) cbk = 0;
    ull bmv = __ballot(fm);
    if (lane == 0) s_fmrow[wv] = bmv;

    const float* base = cm + (size_t)b * 27 * 1024 + tid;
    float v[27];
    float xl = 0.f, s0 = 0.f;
#pragma unroll
    for (int c = 0; c < 27; ++c) {
      float r = __builtin_nontemporal_load(base + (size_t)c * 1024);
      xl = (c == lab) ? r : xl;
      r = __expf(r);
      v[c] = r;
      s0 += r;
    }
    float inv0 = 1.f / s0;
    float ce_part = __logf(s0) - xl;

    float* os = out_smid + (size_t)b * 26 * 1024 + tid;
#pragma unroll
    for (int t = 0; t < TT; ++t) {
      float m1 = v[t + 1] * inv0;
      os[(size_t)t * 1024] = m1;
      float ri = wave_red63(((cbk >> t) & 1) ? m1 : 0.f);
      float rm = wave_red63(m1);
      if (lane == 63) { s_red_in[wv][t] = ri; s_red_m1[wv][t] = rm; }
    }
    float rce = wave_red63(ce_part);
    if (lane == 63) s_ce[wv] = rce;
  }
  __syncthreads();   // B3
  if (tid < TT) {
    float m2v = 0.f;
#pragma unroll
    for (int r = 0; r < 16; ++r) m2v += (float)__popcll(s_fmrow[r] & s_bits[tid]);
    float si = 0.f, sm = 0.f;
#pragma unroll
    for (int w = 0; w < 16; ++w) { si += s_red_in[w][tid]; sm += s_red_m1[w][tid]; }
    int o = b * TT + tid;
    m2s_mid[o] = m2v;
    inter_mid[o] = si;
    m1s_mid[o] = sm;
  }
  if (tid == TT) {
    float c16 = 0.f;
#pragma unroll
    for (int w = 0; w < 16; ++w) c16 += s_ce[w];
    celm_part[b] = c16;
  }
  __syncthreads();   // B4 (protect s_red/s_ce reuse)

  // ---- low branch: 256 px, threads 0..255 ----
  if (tid < 256) {
    int px = tid;
    int y = px >> 5, x = px & 31;
    int wb = 4 * x + 1;
    int word = wb >> 6;
    int p = wb & 63;
    ull r0 = fmsk_lds[(4 * y + 1) * 2 + word];
    ull r1 = fmsk_lds[(4 * y + 2) * 2 + word];
    int cnt = (int)((r0 >> p) & 1) + (int)((r0 >> (p + 1)) & 1)
            + (int)((r1 >> p) & 1) + (int)((r1 >> (p + 1)) & 1);
    bool fm = cnt >= 2;
    unsigned cbk = s_cols_low[x];
    int lab = (fm && cbk) ? __ffs((int)cbk) : 0;
    if (!fm) cbk = 0;
    ull bmv = __ballot(fm);
    if (lane == 0) {
      fmrow32[2 * wv] = (unsigned)bmv;
      fmrow32[2 * wv + 1] = (unsigned)(bmv >> 32);
    }

    const float* base = cl + (size_t)b * 27 * 256 + px;
    float v[27];
    float xl = 0.f, s0 = 0.f;
#pragma unroll
    for (int c = 0; c < 27; ++c) {
      float r = __builtin_nontemporal_load(base + (size_t)c * 256);
      xl = (c == lab) ? r : xl;
      r = __expf(r);
      v[c] = r;
      s0 += r;
    }
    float inv0 = 1.f / s0;
    float ce_part = __logf(s0) - xl;

    float* om  = out_mask + (size_t)b * 27 * 256 + px;
    float* osf = out_slow + (size_t)b * 26 * 256 + px;
    om[0] = fm ? 0.f : 1.f;
#pragma unroll
    for (int t = 0; t < TT; ++t) {
      float m1 = v[t + 1] * inv0;
      osf[(size_t)t * 256] = m1;
      bool m2 = (cbk >> t) & 1;
      om[(size_t)(t + 1) * 256] = m2 ? 1.f : 0.f;
      float ri = wave_red63(m2 ? m1 : 0.f);
      float rm = wave_red63(m1);
      if (lane == 63) { s_red_in[wv][t] = ri; s_red_m1[wv][t] = rm; }
    }
    float rce = wave_red63(ce_part);
    if (lane == 63) s_ce[wv] = rce;
  }
  __syncthreads();   // B5
  if (tid < TT) {
    float m2v = 0.f;
#pragma unroll
    for (int yy = 0; yy < 8; ++yy) m2v += (float)__popc(fmrow32[yy] & s_alow[tid]);
    float si = 0.f, sm = 0.f;
#pragma unroll
    for (int w = 0; w < 4; ++w) { si += s_red_in[w][tid]; sm += s_red_m1[w][tid]; }
    int o = b * TT + tid;
    m2s_low[o] = m2v;
    inter_low[o] = si;
    m1s_low[o] = sm;
  }
  if (tid == TT) cell_part[b] = s_ce[0] + s_ce[1] + s_ce[2] + s_ce[3];
}

// ---------------- finalize scalars ----------------
__global__ __launch_bounds__(1024) void k_final(
    const float* __restrict__ seg_part, const float* __restrict__ cor_part,
    const float* __restrict__ irr_part, const float* __restrict__ celm_part,
    const float* __restrict__ cell_part,
    const float* __restrict__ inter_mid, const float* __restrict__ m1s_mid,
    const float* __restrict__ m2s_mid,
    const float* __restrict__ inter_low, const float* __restrict__ m1s_low,
    const float* __restrict__ m2s_low,
    const int* __restrict__ length, const int* __restrict__ iter_p,
    float* __restrict__ out)
{
  int tid = threadIdx.x;
  float dm = 0.f, dl = 0.f;
  for (int i = tid; i < NB * TT; i += 1024) {
    int b = i / TT, t = i - b * TT;
    int n = length[b] - 1;
    if (t < n) {
      float inv_n = 1.f / (float)n;
      dm += (1.f - (2.f * inter_mid[i] + 1.f) / (m1s_mid[i] + m2s_mid[i] + 1.f)) * inv_n;
      dl += (1.f - (2.f * inter_low[i] + 1.f) / (m1s_low[i] + m2s_low[i] + 1.f)) * inv_n;
    }
  }
  float ss = 0.f, sel = 0.f, ssel = 0.f;
  float irr = 0.f, cell = 0.f, celm = 0.f, cor = 0.f;
  for (int b = tid; b < NB; b += 1024) {
    float v = seg_part[b];
    ss += v;
    float val = v * (1.f / 4096.f);
    if (val < 1.f) { sel += 1.f; ssel += val; }
    irr += irr_part[b]; cell += cell_part[b]; celm += celm_part[b]; cor += cor_part[b];
  }

  dm = wave_sum(dm); dl = wave_sum(dl); ss = wave_sum(ss);
  sel = wave_sum(sel); ssel = wave_sum(ssel);
  irr = wave_sum(irr); celm = wave_sum(celm); cell = wave_sum(cell);
  cor = wave_sum(cor);
  __shared__ float red[9][16];
  int wv = tid >> 6;
  if ((tid & 63) == 0) {
    red[0][wv] = dm; red[1][wv] = dl; red[2][wv] = ss; red[3][wv] = sel;
    red[4][wv] = ssel; red[5][wv] = irr; red[6][wv] = celm; red[7][wv] = cell;
    red[8][wv] = cor;
  }
  __syncthreads();
  if (tid == 0) {
    float a[9];
#pragma unroll
    for (int j = 0; j < 9; ++j) {
      float s = 0.f;
      for (int i = 0; i < 16; ++i) s += red[j][i];
      a[j] = s;
    }
    float pred = (iter_p[0] > 20000) ? (a[4] / fmaxf(a[3], 1.f)) : (a[2] / 2097152.f);
    out[0] = pred;
    out[1] = a[8] / 2097152.f + a[5];
    out[2] = a[7] / 131072.f + a[1] / 512.f;   // loss_low
    out[3] = a[6] / 524288.f + a[0] / 512.f;   // loss_middle
  }
}

extern "C" void kernel_launch(void* const* d_in, const int* in_sizes, int n_in,
                              void* d_out, int out_size, void* d_ws, size_t ws_size,
                              hipStream_t stream) {
  (void)in_sizes; (void)n_in; (void)out_size; (void)ws_size;
  const float* masks  = (const float*)d_in[0];
  const float* bf     = (const float*)d_in[1];
  const float* seq    = (const float*)d_in[2];
  const float* cmid   = (const float*)d_in[3];
  const float* clow   = (const float*)d_in[4];
  const int*   length = (const int*)d_in[5];
  const int*   iter   = (const int*)d_in[6];
  const float* alpha  = (const float*)d_in[7];
  float* out = (float*)d_out;

  char* ws = (char*)d_ws;
  // all scratch fully rewritten every launch -> no memset
  float* seg_part  = (float*)(ws + 0);        // 512 f32
  float* cor_part  = (float*)(ws + 2048);     // 512
  float* irr_part  = (float*)(ws + 4096);     // 512
  float* celm_part = (float*)(ws + 6144);     // 512
  float* cell_part = (float*)(ws + 8192);     // 512
  float* inter_mid = (float*)(ws + 10240);    // 13312 f32 each
  float* m1s_mid   = (float*)(ws + 63488);
  float* m2s_mid   = (float*)(ws + 116736);
  float* inter_low = (float*)(ws + 169984);
  float* m1s_low   = (float*)(ws + 223232);
  float* m2s_low   = (float*)(ws + 276480);   // ends 329728

  float* out_mask = out + 4;
  float* out_smid = out + 4 + 3538944;
  float* out_slow = out + 4 + 3538944 + 13631488;

  k_mega<<<NB, 1024, 0, stream>>>(masks, bf, seq, cmid, clow, length, alpha,
                                  out_mask, out_smid, out_slow,
                                  seg_part, cor_part, irr_part, celm_part, cell_part,
                                  inter_mid, m1s_mid, m2s_mid,
                                  inter_low, m1s_low, m2s_low);
  k_final<<<1, 1024, 0, stream>>>(seg_part, cor_part, irr_part, celm_part, cell_part,
                                  inter_mid, m1s_mid, m2s_mid,
                                  inter_low, m1s_low, m2s_low, length, iter, out);
}

// Round 11
// 68.943 us; speedup vs baseline: 1.0237x; 1.0237x over previous
//
#include <hip/hip_runtime.h>
#include <math.h>

#define NB 512
#define TT 26
#define LL 64
#define HH 32
#define WW 128

typedef unsigned long long ull;

__device__ __forceinline__ float wave_sum(float v) {
#pragma unroll
  for (int o = 32; o > 0; o >>= 1) v += __shfl_xor(v, o, 64);
  return v;
}

template<int CTRL, int RM>
__device__ __forceinline__ float dpp_add(float x) {
  int y = __builtin_amdgcn_update_dpp(0, __float_as_int(x), CTRL, RM, 0xf, true);
  return x + __int_as_float(y);
}
// sum across 64 lanes via DPP (VALU pipe only); result valid in lane 63
__device__ __forceinline__ float wave_red63(float x) {
  x = dpp_add<0x111, 0xf>(x);   // row_shr:1
  x = dpp_add<0x112, 0xf>(x);   // row_shr:2
  x = dpp_add<0x114, 0xf>(x);   // row_shr:4
  x = dpp_add<0x118, 0xf>(x);   // row_shr:8
  x = dpp_add<0x142, 0xa>(x);   // row_bcast15 -> rows 1,3
  x = dpp_add<0x143, 0xc>(x);   // row_bcast31 -> rows 2,3; lane63 = total
  return x;
}

// ================= Mega kernel: one block per sample b, 1024 threads =================
__global__ __launch_bounds__(1024) void k_mega(
    const float* __restrict__ masks, const float* __restrict__ bf,
    const float* __restrict__ seq, const float* __restrict__ cm,
    const float* __restrict__ cl, const int* __restrict__ length,
    const float* __restrict__ alpha_p,
    float* __restrict__ out_mask, float* __restrict__ out_smid,
    float* __restrict__ out_slow,
    float* __restrict__ seg_part, float* __restrict__ cor_part,
    float* __restrict__ irr_part, float* __restrict__ celm_part,
    float* __restrict__ cell_part,
    float* __restrict__ inter_mid, float* __restrict__ m1s_mid, float* __restrict__ m2s_mid,
    float* __restrict__ inter_low, float* __restrict__ m1s_low, float* __restrict__ m2s_low)
{
  int b = blockIdx.x;
  int tid = threadIdx.x;
  int lane = tid & 63, wv = tid >> 6;

  __shared__ float att[LL * TT];          // [l][t]
  __shared__ float wsA_lds[WW];
  __shared__ ull s_bits[TT];              // amid bitmasks (64 cols)
  __shared__ unsigned s_alow[TT];         // alow bitmasks (32 cols)
  __shared__ unsigned s_cols_mid[64];
  __shared__ unsigned s_cols_low[32];
  __shared__ ull fmsk_lds[64];            // fore mask, 32 rows x 2 words
  __shared__ ull s_fmrow[16];             // mid fm row masks
  __shared__ unsigned fmrow32[8];         // low fm row masks
  __shared__ float s_red_in[16][TT], s_red_m1[16][TT];
  __shared__ float s_ce[16];
  __shared__ float ps[16], pc[16];
  __shared__ float wpart[2];

  int n = length[b] - 1;
  float alpha = alpha_p[0];

  // ---- load attention [64][26] (issued FIRST so the B0 wait is counted, not full-drain) ----
  const float* sb = seq + (size_t)b * (LL * TT);
  float a0 = sb[tid];
  float a1 = (tid < LL * TT - 1024) ? sb[1024 + tid] : 0.f;

  // ---- HOISTED: issue the 27 cm channel loads now; consumed only after B2 ----
  // This keeps the dominant 56.6MB read stream in flight under phases 0-2.
  const float* base_cm = cm + (size_t)b * 27 * 1024 + tid;
  float vraw[27];
#pragma unroll
  for (int c = 0; c < 27; ++c) vraw[c] = base_cm[(size_t)c * 1024];

  att[tid] = a0;
  if (tid < LL * TT - 1024) att[1024 + tid] = a1;
  __syncthreads();   // B0

  // ---- phase 1: interp sums + bitmasks (threads 0..127) ----
  if (tid < 128) {
    int w = tid;
    int k = w >> 1;
    int i0, i1; float c0, c1;
    if ((w & 1) == 0) {
      if (k == 0) { i0 = 0; i1 = 0; c0 = 1.f; c1 = 0.f; }
      else        { i0 = k - 1; i1 = k; c0 = 0.25f; c1 = 0.75f; }
    } else {
      if (k == 63) { i0 = 63; i1 = 63; c0 = 1.f; c1 = 0.f; }
      else         { i0 = k; i1 = k + 1; c0 = 0.75f; c1 = 0.25f; }
    }
    float S = 0.f, S2 = 0.f, A = 0.f;
    for (int t = 0; t < n; ++t) {
      float v = c0 * att[i0 * TT + t] + c1 * att[i1 * TT + t];
      float s = v * v;
      S += s; S2 += s * s;
      A += 1.f / (1.f + __expf(-70.f * (v - 0.1f)));
    }
    wsA_lds[w] = A;
    float c = S * S - S2;
    c = wave_sum(c);
    if (lane == 0) wpart[wv] = c;
  }
  if (tid < 64) {
    int x = tid;                       // middle: identity resize, 64 cols
    for (int t = 0; t < TT; ++t) {
      bool pred = (t < n) && (att[x * TT + t] > alpha);
      ull m = __ballot(pred);
      if (x == 0) s_bits[t] = m;
    }
  } else if (tid < 128) {
    int x = tid - 64;                  // low: pairwise mean, 32 cols
    for (int t = 0; t < TT; ++t) {
      bool pred = (x < 32) && (t < n) &&
                  (0.5f * (att[(2 * x) * TT + t] + att[(2 * x + 1) * TT + t]) > alpha);
      ull m = __ballot(pred);
      if (x == 0) s_alow[t] = (unsigned)m;
    }
  }
  __syncthreads();   // B1
  if (tid == 0) irr_part[b] = 0.5f * (wpart[0] + wpart[1]) / (float)n;

  // ---- column bitmasks (t-bits per column) ----
  if (tid < 64) {
    unsigned cb = 0;
#pragma unroll
    for (int t = 0; t < TT; ++t) cb |= (unsigned)((s_bits[t] >> tid) & 1ULL) << t;
    s_cols_mid[tid] = cb;
  } else if (tid < 96) {
    int xc = tid - 64;
    unsigned cb = 0;
#pragma unroll
    for (int t = 0; t < TT; ++t) cb |= ((s_alow[t] >> xc) & 1u) << t;
    s_cols_low[xc] = cb;
  }

  // ---- phase 2: seg CE + correct CE + fore mask (all threads, 4 px each) ----
  {
    const float* mb = masks + (size_t)b * 4096;
    const float* fb = bf + (size_t)b * 8192;
    float A = wsA_lds[tid & 127];
    float cs = fminf(fmaxf(A, 0.f), 1.f);
    float ce_fore = log1pf(__expf(1.f - 2.f * cs));
    float seg_acc = 0.f, cor_acc = 0.f;
    for (int k = 0; k < 4; ++k) {
      int px = k * 1024 + tid;
      float m = mb[px];
      float b0 = fb[px];
      float b1 = fb[4096 + px];
      float mx = fmaxf(b0, b1);
      float e0 = __expf(b0 - mx), e1 = __expf(b1 - mx);
      float inv = 1.f / (e0 + e1);
      float p0 = e0 * inv, p1 = e1 * inv;
      float pm = fmaxf(p0, p1);
      float lse = pm + log1pf(__expf(-fabsf(p1 - p0)));
      seg_acc += lse - ((m > 0.5f) ? p1 : p0);
      bool fore = b1 > b0;
      cor_acc += fore ? ce_fore : 0.313261687518222834f;
      ull fbm = __ballot(fore);
      if (lane == 0) fmsk_lds[k * 16 + wv] = fbm;
    }
    seg_acc = wave_red63(seg_acc);
    cor_acc = wave_red63(cor_acc);
    if (lane == 63) { ps[wv] = seg_acc; pc[wv] = cor_acc; }
  }
  __syncthreads();   // B2
  if (tid == 0) {
    float s = 0.f, c = 0.f;
#pragma unroll
    for (int i = 0; i < 16; ++i) { s += ps[i]; c += pc[i]; }
    seg_part[b] = s;
    cor_part[b] = c;
  }

  // ---- mid branch: 1024 px, 1 px/thread; wave == row y; consumes hoisted vraw ----
  {
    int y = wv;                  // 0..15
    int x = tid & 63;
    int word = x >> 5;
    int p = (x & 31) * 2;
    ull r0 = fmsk_lds[4 * y + word];
    ull r1 = fmsk_lds[4 * y + 2 + word];
    int cnt = (int)((r0 >> p) & 1) + (int)((r0 >> (p + 1)) & 1)
            + (int)((r1 >> p) & 1) + (int)((r1 >> (p + 1)) & 1);
    bool fm = cnt >= 2;
    unsigned cbk = s_cols_mid[x];
    int lab = (fm && cbk) ? __ffs((int)cbk) : 0;
    if (!fm) cbk = 0;
    ull bmv = __ballot(fm);
    if (lane == 0) s_fmrow[wv] = bmv;

    float v[27];
    float xl = 0.f, s0 = 0.f;
#pragma unroll
    for (int c = 0; c < 27; ++c) {
      float r = vraw[c];
      xl = (c == lab) ? r : xl;
      r = __expf(r);
      v[c] = r;
      s0 += r;
    }
    float inv0 = 1.f / s0;
    float ce_part = __logf(s0) - xl;

    float* os = out_smid + (size_t)b * 26 * 1024 + tid;
#pragma unroll
    for (int t = 0; t < TT; ++t) {
      float m1 = v[t + 1] * inv0;
      os[(size_t)t * 1024] = m1;
      float ri = wave_red63(((cbk >> t) & 1) ? m1 : 0.f);
      float rm = wave_red63(m1);
      if (lane == 63) { s_red_in[wv][t] = ri; s_red_m1[wv][t] = rm; }
    }
    float rce = wave_red63(ce_part);
    if (lane == 63) s_ce[wv] = rce;
  }
  __syncthreads();   // B3
  if (tid < TT) {
    float m2v = 0.f;
#pragma unroll
    for (int r = 0; r < 16; ++r) m2v += (float)__popcll(s_fmrow[r] & s_bits[tid]);
    float si = 0.f, sm = 0.f;
#pragma unroll
    for (int w = 0; w < 16; ++w) { si += s_red_in[w][tid]; sm += s_red_m1[w][tid]; }
    int o = b * TT + tid;
    m2s_mid[o] = m2v;
    inter_mid[o] = si;
    m1s_mid[o] = sm;
  }
  if (tid == TT) {
    float c16 = 0.f;
#pragma unroll
    for (int w = 0; w < 16; ++w) c16 += s_ce[w];
    celm_part[b] = c16;
  }
  __syncthreads();   // B4 (protect s_red/s_ce reuse)

  // ---- low branch: 256 px, threads 0..255 ----
  if (tid < 256) {
    int px = tid;
    int y = px >> 5, x = px & 31;
    int wb = 4 * x + 1;
    int word = wb >> 6;
    int p = wb & 63;
    ull r0 = fmsk_lds[(4 * y + 1) * 2 + word];
    ull r1 = fmsk_lds[(4 * y + 2) * 2 + word];
    int cnt = (int)((r0 >> p) & 1) + (int)((r0 >> (p + 1)) & 1)
            + (int)((r1 >> p) & 1) + (int)((r1 >> (p + 1)) & 1);
    bool fm = cnt >= 2;
    unsigned cbk = s_cols_low[x];
    int lab = (fm && cbk) ? __ffs((int)cbk) : 0;
    if (!fm) cbk = 0;
    ull bmv = __ballot(fm);
    if (lane == 0) {
      fmrow32[2 * wv] = (unsigned)bmv;
      fmrow32[2 * wv + 1] = (unsigned)(bmv >> 32);
    }

    const float* base = cl + (size_t)b * 27 * 256 + px;
    float v[27];
    float xl = 0.f, s0 = 0.f;
#pragma unroll
    for (int c = 0; c < 27; ++c) {
      float r = base[(size_t)c * 256];
      xl = (c == lab) ? r : xl;
      r = __expf(r);
      v[c] = r;
      s0 += r;
    }
    float inv0 = 1.f / s0;
    float ce_part = __logf(s0) - xl;

    float* om  = out_mask + (size_t)b * 27 * 256 + px;
    float* osf = out_slow + (size_t)b * 26 * 256 + px;
    om[0] = fm ? 0.f : 1.f;
#pragma unroll
    for (int t = 0; t < TT; ++t) {
      float m1 = v[t + 1] * inv0;
      osf[(size_t)t * 256] = m1;
      bool m2 = (cbk >> t) & 1;
      om[(size_t)(t + 1) * 256] = m2 ? 1.f : 0.f;
      float ri = wave_red63(m2 ? m1 : 0.f);
      float rm = wave_red63(m1);
      if (lane == 63) { s_red_in[wv][t] = ri; s_red_m1[wv][t] = rm; }
    }
    float rce = wave_red63(ce_part);
    if (lane == 63) s_ce[wv] = rce;
  }
  __syncthreads();   // B5
  if (tid < TT) {
    float m2v = 0.f;
#pragma unroll
    for (int yy = 0; yy < 8; ++yy) m2v += (float)__popc(fmrow32[yy] & s_alow[tid]);
    float si = 0.f, sm = 0.f;
#pragma unroll
    for (int w = 0; w < 4; ++w) { si += s_red_in[w][tid]; sm += s_red_m1[w][tid]; }
    int o = b * TT + tid;
    m2s_low[o] = m2v;
    inter_low[o] = si;
    m1s_low[o] = sm;
  }
  if (tid == TT) cell_part[b] = s_ce[0] + s_ce[1] + s_ce[2] + s_ce[3];
}

// ---------------- finalize scalars ----------------
__global__ __launch_bounds__(1024) void k_final(
    const float* __restrict__ seg_part, const float* __restrict__ cor_part,
    const float* __restrict__ irr_part, const float* __restrict__ celm_part,
    const float* __restrict__ cell_part,
    const float* __restrict__ inter_mid, const float* __restrict__ m1s_mid,
    const float* __restrict__ m2s_mid,
    const float* __restrict__ inter_low, const float* __restrict__ m1s_low,
    const float* __restrict__ m2s_low,
    const int* __restrict__ length, const int* __restrict__ iter_p,
    float* __restrict__ out)
{
  int tid = threadIdx.x;
  float dm = 0.f, dl = 0.f;
  for (int i = tid; i < NB * TT; i += 1024) {
    int b = i / TT, t = i - b * TT;
    int n = length[b] - 1;
    if (t < n) {
      float inv_n = 1.f / (float)n;
      dm += (1.f - (2.f * inter_mid[i] + 1.f) / (m1s_mid[i] + m2s_mid[i] + 1.f)) * inv_n;
      dl += (1.f - (2.f * inter_low[i] + 1.f) / (m1s_low[i] + m2s_low[i] + 1.f)) * inv_n;
    }
  }
  float ss = 0.f, sel = 0.f, ssel = 0.f;
  float irr = 0.f, cell = 0.f, celm = 0.f, cor = 0.f;
  for (int b = tid; b < NB; b += 1024) {
    float v = seg_part[b];
    ss += v;
    float val = v * (1.f / 4096.f);
    if (val < 1.f) { sel += 1.f; ssel += val; }
    irr += irr_part[b]; cell += cell_part[b]; celm += celm_part[b]; cor += cor_part[b];
  }

  dm = wave_sum(dm); dl = wave_sum(dl); ss = wave_sum(ss);
  sel = wave_sum(sel); ssel = wave_sum(ssel);
  irr = wave_sum(irr); celm = wave_sum(celm); cell = wave_sum(cell);
  cor = wave_sum(cor);
  __shared__ float red[9][16];
  int wv = tid >> 6;
  if ((tid & 63) == 0) {
    red[0][wv] = dm; red[1][wv] = dl; red[2][wv] = ss; red[3][wv] = sel;
    red[4][wv] = ssel; red[5][wv] = irr; red[6][wv] = celm; red[7][wv] = cell;
    red[8][wv] = cor;
  }
  __syncthreads();
  if (tid == 0) {
    float a[9];
#pragma unroll
    for (int j = 0; j < 9; ++j) {
      float s = 0.f;
      for (int i = 0; i < 16; ++i) s += red[j][i];
      a[j] = s;
    }
    float pred = (iter_p[0] > 20000) ? (a[4] / fmaxf(a[3], 1.f)) : (a[2] / 2097152.f);
    out[0] = pred;
    out[1] = a[8] / 2097152.f + a[5];
    out[2] = a[7] / 131072.f + a[1] / 512.f;   // loss_low
    out[3] = a[6] / 524288.f + a[0] / 512.f;   // loss_middle
  }
}

extern "C" void kernel_launch(void* const* d_in, const int* in_sizes, int n_in,
                              void* d_out, int out_size, void* d_ws, size_t ws_size,
                              hipStream_t stream) {
  (void)in_sizes; (void)n_in; (void)out_size; (void)ws_size;
  const float* masks  = (const float*)d_in[0];
  const float* bf     = (const float*)d_in[1];
  const float* seq    = (const float*)d_in[2];
  const float* cmid   = (const float*)d_in[3];
  const float* clow   = (const float*)d_in[4];
  const int*   length = (const int*)d_in[5];
  const int*   iter   = (const int*)d_in[6];
  const float* alpha  = (const float*)d_in[7];
  float* out = (float*)d_out;

  char* ws = (char*)d_ws;
  // all scratch fully rewritten every launch -> no memset
  float* seg_part  = (float*)(ws + 0);        // 512 f32
  float* cor_part  = (float*)(ws + 2048);     // 512
  float* irr_part  = (float*)(ws + 4096);     // 512
  float* celm_part = (float*)(ws + 6144);     // 512
  float* cell_part = (float*)(ws + 8192);     // 512
  float* inter_mid = (float*)(ws + 10240);    // 13312 f32 each
  float* m1s_mid   = (float*)(ws + 63488);
  float* m2s_mid   = (float*)(ws + 116736);
  float* inter_low = (float*)(ws + 169984);
  float* m1s_low   = (float*)(ws + 223232);
  float* m2s_low   = (float*)(ws + 276480);   // ends 329728

  float* out_mask = out + 4;
  float* out_smid = out + 4 + 3538944;
  float* out_slow = out + 4 + 3538944 + 13631488;

  k_mega<<<NB, 1024, 0, stream>>>(masks, bf, seq, cmid, clow, length, alpha,
                                  out_mask, out_smid, out_slow,
                                  seg_part, cor_part, irr_part, celm_part, cell_part,
                                  inter_mid, m1s_mid, m2s_mid,
                                  inter_low, m1s_low, m2s_low);
  k_final<<<1, 1024, 0, stream>>>(seg_part, cor_part, irr_part, celm_part, cell_part,
                                  inter_mid, m1s_mid, m2s_mid,
                                  inter_low, m1s_low, m2s_low, length, iter, out);
}

// Round 12
// 54.814 us; speedup vs baseline: 1.2875x; 1.2578x over previous
//
#include <hip/hip_runtime.h>
#include <math.h>

#define NB 512
#define TT 26
#define LL 64
#define HH 32
#define WW 128

typedef unsigned long long ull;

__device__ __forceinline__ float wave_sum(float v) {
#pragma unroll
  for (int o = 32; o > 0; o >>= 1) v += __shfl_xor(v, o, 64);
  return v;
}

template<int CTRL, int RM>
__device__ __forceinline__ float dpp_add(float x) {
  int y = __builtin_amdgcn_update_dpp(0, __float_as_int(x), CTRL, RM, 0xf, true);
  return x + __int_as_float(y);
}
// sum across 64 lanes via DPP (VALU pipe only); result valid in lane 63
__device__ __forceinline__ float wave_red63(float x) {
  x = dpp_add<0x111, 0xf>(x);   // row_shr:1
  x = dpp_add<0x112, 0xf>(x);   // row_shr:2
  x = dpp_add<0x114, 0xf>(x);   // row_shr:4
  x = dpp_add<0x118, 0xf>(x);   // row_shr:8
  x = dpp_add<0x142, 0xa>(x);   // row_bcast15 -> rows 1,3
  x = dpp_add<0x143, 0xc>(x);   // row_bcast31 -> rows 2,3; lane63 = total
  return x;
}

// perb[b][i]: 0 seg, 1 cor, 2 irr, 3 celm, 4 cell, 5 dm, 6 dl, 7 pad

// ================= Mega kernel: one block per sample b, 1024 threads =================
__global__ __launch_bounds__(1024) void k_mega(
    const float* __restrict__ masks, const float* __restrict__ bf,
    const float* __restrict__ seq, const float* __restrict__ cm,
    const float* __restrict__ cl, const int* __restrict__ length,
    const float* __restrict__ alpha_p,
    float* __restrict__ out_mask, float* __restrict__ out_smid,
    float* __restrict__ out_slow, float* __restrict__ perb)
{
  int b = blockIdx.x;
  int tid = threadIdx.x;
  int lane = tid & 63, wv = tid >> 6;

  __shared__ float att[LL * TT];          // [l][t]
  __shared__ float wsA_lds[WW];
  __shared__ ull s_bits[TT];              // amid bitmasks (64 cols)
  __shared__ unsigned s_alow[TT];         // alow bitmasks (32 cols)
  __shared__ unsigned s_cols_mid[64];
  __shared__ unsigned s_cols_low[32];
  __shared__ ull fmsk_lds[64];            // fore mask, 32 rows x 2 words
  __shared__ ull s_fmrow[16];             // mid fm row masks
  __shared__ unsigned fmrow32[8];         // low fm row masks
  __shared__ float s_red_in[16][TT], s_red_m1[16][TT];
  __shared__ float s_ce[16];
  __shared__ float ps[16], pc[16];
  __shared__ float wpart[2];
  __shared__ float s_dice[TT];

  int n = length[b] - 1;
  float alpha = alpha_p[0];
  float inv_n = 1.f / (float)n;

  // ---- load attention [64][26] ----
  const float* sb = seq + (size_t)b * (LL * TT);
  for (int i = tid; i < LL * TT; i += 1024) att[i] = sb[i];
  __syncthreads();   // B0

  // ---- phase 1: interp sums + bitmasks (threads 0..127) ----
  if (tid < 128) {
    int w = tid;
    int k = w >> 1;
    int i0, i1; float c0, c1;
    if ((w & 1) == 0) {
      if (k == 0) { i0 = 0; i1 = 0; c0 = 1.f; c1 = 0.f; }
      else        { i0 = k - 1; i1 = k; c0 = 0.25f; c1 = 0.75f; }
    } else {
      if (k == 63) { i0 = 63; i1 = 63; c0 = 1.f; c1 = 0.f; }
      else         { i0 = k; i1 = k + 1; c0 = 0.75f; c1 = 0.25f; }
    }
    float S = 0.f, S2 = 0.f, A = 0.f;
    for (int t = 0; t < n; ++t) {
      float v = c0 * att[i0 * TT + t] + c1 * att[i1 * TT + t];
      float s = v * v;
      S += s; S2 += s * s;
      A += 1.f / (1.f + __expf(-70.f * (v - 0.1f)));
    }
    wsA_lds[w] = A;
    float c = S * S - S2;
    c = wave_sum(c);
    if (lane == 0) wpart[wv] = c;
  }
  if (tid < 64) {
    int x = tid;                       // middle: identity resize, 64 cols
    for (int t = 0; t < TT; ++t) {
      bool pred = (t < n) && (att[x * TT + t] > alpha);
      ull m = __ballot(pred);
      if (x == 0) s_bits[t] = m;
    }
  } else if (tid < 128) {
    int x = tid - 64;                  // low: pairwise mean, 32 cols
    for (int t = 0; t < TT; ++t) {
      bool pred = (x < 32) && (t < n) &&
                  (0.5f * (att[(2 * x) * TT + t] + att[(2 * x + 1) * TT + t]) > alpha);
      ull m = __ballot(pred);
      if (x == 0) s_alow[t] = (unsigned)m;
    }
  }
  __syncthreads();   // B1
  if (tid == 0) perb[b * 8 + 2] = 0.5f * (wpart[0] + wpart[1]) * inv_n;

  // ---- column bitmasks (t-bits per column) ----
  if (tid < 64) {
    unsigned cb = 0;
#pragma unroll
    for (int t = 0; t < TT; ++t) cb |= (unsigned)((s_bits[t] >> tid) & 1ULL) << t;
    s_cols_mid[tid] = cb;
  } else if (tid < 96) {
    int xc = tid - 64;
    unsigned cb = 0;
#pragma unroll
    for (int t = 0; t < TT; ++t) cb |= ((s_alow[t] >> xc) & 1u) << t;
    s_cols_low[xc] = cb;
  }

  // ---- phase 2: seg CE + correct CE + fore mask (all threads, 4 px each) ----
  {
    const float* mb = masks + (size_t)b * 4096;
    const float* fb = bf + (size_t)b * 8192;
    float A = wsA_lds[tid & 127];
    float cs = fminf(fmaxf(A, 0.f), 1.f);
    float ce_fore = log1pf(__expf(1.f - 2.f * cs));
    float seg_acc = 0.f, cor_acc = 0.f;
    for (int k = 0; k < 4; ++k) {
      int px = k * 1024 + tid;
      float m = mb[px];
      float b0 = fb[px];
      float b1 = fb[4096 + px];
      float mx = fmaxf(b0, b1);
      float e0 = __expf(b0 - mx), e1 = __expf(b1 - mx);
      float inv = 1.f / (e0 + e1);
      float p0 = e0 * inv, p1 = e1 * inv;
      float pm = fmaxf(p0, p1);
      float lse = pm + log1pf(__expf(-fabsf(p1 - p0)));
      seg_acc += lse - ((m > 0.5f) ? p1 : p0);
      bool fore = b1 > b0;
      cor_acc += fore ? ce_fore : 0.313261687518222834f;
      ull fbm = __ballot(fore);
      if (lane == 0) fmsk_lds[k * 16 + wv] = fbm;
    }
    seg_acc = wave_red63(seg_acc);
    cor_acc = wave_red63(cor_acc);
    if (lane == 63) { ps[wv] = seg_acc; pc[wv] = cor_acc; }
  }
  __syncthreads();   // B2
  if (tid == 0) {
    float s = 0.f, c = 0.f;
#pragma unroll
    for (int i = 0; i < 16; ++i) { s += ps[i]; c += pc[i]; }
    perb[b * 8 + 0] = s;
    perb[b * 8 + 1] = c;
  }

  // ---- mid branch: 1024 px, 1 px/thread; wave == row y ----
  {
    int y = wv;                  // 0..15
    int x = tid & 63;
    int word = x >> 5;
    int p = (x & 31) * 2;
    ull r0 = fmsk_lds[4 * y + word];
    ull r1 = fmsk_lds[4 * y + 2 + word];
    int cnt = (int)((r0 >> p) & 1) + (int)((r0 >> (p + 1)) & 1)
            + (int)((r1 >> p) & 1) + (int)((r1 >> (p + 1)) & 1);
    bool fm = cnt >= 2;
    unsigned cbk = s_cols_mid[x];
    int lab = (fm && cbk) ? __ffs((int)cbk) : 0;
    if (!fm) cbk = 0;
    ull bmv = __ballot(fm);
    if (lane == 0) s_fmrow[wv] = bmv;

    const float* base = cm + (size_t)b * 27 * 1024 + tid;
    float v[27];
    float xl = 0.f, s0 = 0.f;
#pragma unroll
    for (int c = 0; c < 27; ++c) {
      float r = base[(size_t)c * 1024];
      xl = (c == lab) ? r : xl;
      r = __expf(r);
      v[c] = r;
      s0 += r;
    }
    float inv0 = 1.f / s0;
    float ce_part = __logf(s0) - xl;

    float* os = out_smid + (size_t)b * 26 * 1024 + tid;
#pragma unroll
    for (int t = 0; t < TT; ++t) {
      float m1 = v[t + 1] * inv0;
      os[(size_t)t * 1024] = m1;
      float ri = wave_red63(((cbk >> t) & 1) ? m1 : 0.f);
      float rm = wave_red63(m1);
      if (lane == 63) { s_red_in[wv][t] = ri; s_red_m1[wv][t] = rm; }
    }
    float rce = wave_red63(ce_part);
    if (lane == 63) s_ce[wv] = rce;
  }
  __syncthreads();   // B3
  if (tid < TT) {
    float m2v = 0.f;
#pragma unroll
    for (int r = 0; r < 16; ++r) m2v += (float)__popcll(s_fmrow[r] & s_bits[tid]);
    float si = 0.f, sm = 0.f;
#pragma unroll
    for (int w = 0; w < 16; ++w) { si += s_red_in[w][tid]; sm += s_red_m1[w][tid]; }
    float sc = (2.f * si + 1.f) / (sm + m2v + 1.f);
    s_dice[tid] = (tid < n) ? (1.f - sc) * inv_n : 0.f;
  }
  if (tid == TT) {
    float c16 = 0.f;
#pragma unroll
    for (int w = 0; w < 16; ++w) c16 += s_ce[w];
    perb[b * 8 + 3] = c16;
  }
  __syncthreads();   // B4 (protect s_red/s_ce reuse; s_dice ready)
  if (tid == 0) {
    float dm = 0.f;
#pragma unroll
    for (int t = 0; t < TT; ++t) dm += s_dice[t];
    perb[b * 8 + 5] = dm;
  }

  // ---- low branch: 256 px, threads 0..255 ----
  if (tid < 256) {
    int px = tid;
    int y = px >> 5, x = px & 31;
    int wb = 4 * x + 1;
    int word = wb >> 6;
    int p = wb & 63;
    ull r0 = fmsk_lds[(4 * y + 1) * 2 + word];
    ull r1 = fmsk_lds[(4 * y + 2) * 2 + word];
    int cnt = (int)((r0 >> p) & 1) + (int)((r0 >> (p + 1)) & 1)
            + (int)((r1 >> p) & 1) + (int)((r1 >> (p + 1)) & 1);
    bool fm = cnt >= 2;
    unsigned cbk = s_cols_low[x];
    int lab = (fm && cbk) ? __ffs((int)cbk) : 0;
    if (!fm) cbk = 0;
    ull bmv = __ballot(fm);
    if (lane == 0) {
      fmrow32[2 * wv] = (unsigned)bmv;
      fmrow32[2 * wv + 1] = (unsigned)(bmv >> 32);
    }

    const float* base = cl + (size_t)b * 27 * 256 + px;
    float v[27];
    float xl = 0.f, s0 = 0.f;
#pragma unroll
    for (int c = 0; c < 27; ++c) {
      float r = base[(size_t)c * 256];
      xl = (c == lab) ? r : xl;
      r = __expf(r);
      v[c] = r;
      s0 += r;
    }
    float inv0 = 1.f / s0;
    float ce_part = __logf(s0) - xl;

    float* om  = out_mask + (size_t)b * 27 * 256 + px;
    float* osf = out_slow + (size_t)b * 26 * 256 + px;
    om[0] = fm ? 0.f : 1.f;
#pragma unroll
    for (int t = 0; t < TT; ++t) {
      float m1 = v[t + 1] * inv0;
      osf[(size_t)t * 256] = m1;
      bool m2 = (cbk >> t) & 1;
      om[(size_t)(t + 1) * 256] = m2 ? 1.f : 0.f;
      float ri = wave_red63(m2 ? m1 : 0.f);
      float rm = wave_red63(m1);
      if (lane == 63) { s_red_in[wv][t] = ri; s_red_m1[wv][t] = rm; }
    }
    float rce = wave_red63(ce_part);
    if (lane == 63) s_ce[wv] = rce;
  }
  __syncthreads();   // B5
  if (tid < TT) {
    float m2v = 0.f;
#pragma unroll
    for (int yy = 0; yy < 8; ++yy) m2v += (float)__popc(fmrow32[yy] & s_alow[tid]);
    float si = 0.f, sm = 0.f;
#pragma unroll
    for (int w = 0; w < 4; ++w) { si += s_red_in[w][tid]; sm += s_red_m1[w][tid]; }
    float sc = (2.f * si + 1.f) / (sm + m2v + 1.f);
    s_dice[tid] = (tid < n) ? (1.f - sc) * inv_n : 0.f;
  }
  if (tid == TT) perb[b * 8 + 4] = s_ce[0] + s_ce[1] + s_ce[2] + s_ce[3];
  __syncthreads();   // B6
  if (tid == 0) {
    float dl = 0.f;
#pragma unroll
    for (int t = 0; t < TT; ++t) dl += s_dice[t];
    perb[b * 8 + 6] = dl;
  }
}

// ---------------- finalize scalars: 512 threads, one per b ----------------
__global__ __launch_bounds__(512) void k_final(
    const float* __restrict__ perb, const int* __restrict__ iter_p,
    float* __restrict__ out)
{
  int tid = threadIdx.x;
  const float4* pb4 = (const float4*)perb;
  float4 p0 = pb4[2 * tid];
  float4 p1 = pb4[2 * tid + 1];
  float seg = p0.x, cor = p0.y, irr = p0.z, celm = p0.w;
  float cell = p1.x, dm = p1.y, dl = p1.z;

  float val = seg * (1.f / 4096.f);
  float sel = (val < 1.f) ? 1.f : 0.f;
  float ssel = (val < 1.f) ? val : 0.f;

  float q[9] = {seg, cor, irr, celm, cell, dm, dl, sel, ssel};
  __shared__ float red[9][8];
  int lane = tid & 63, wv = tid >> 6;
#pragma unroll
  for (int j = 0; j < 9; ++j) {
    float r = wave_sum(q[j]);
    if (lane == 0) red[j][wv] = r;
  }
  __syncthreads();
  if (tid == 0) {
    float a[9];
#pragma unroll
    for (int j = 0; j < 9; ++j) {
      float s = 0.f;
      for (int i = 0; i < 8; ++i) s += red[j][i];
      a[j] = s;
    }
    // a: 0 SS, 1 COR, 2 IRR, 3 CELM, 4 CELL, 5 DM, 6 DL, 7 SEL, 8 SSEL
    float pred = (iter_p[0] > 20000) ? (a[8] / fmaxf(a[7], 1.f)) : (a[0] / 2097152.f);
    out[0] = pred;
    out[1] = a[1] / 2097152.f + a[2];
    out[2] = a[4] / 131072.f + a[6] / 512.f;   // loss_low
    out[3] = a[3] / 524288.f + a[5] / 512.f;   // loss_middle
  }
}

extern "C" void kernel_launch(void* const* d_in, const int* in_sizes, int n_in,
                              void* d_out, int out_size, void* d_ws, size_t ws_size,
                              hipStream_t stream) {
  (void)in_sizes; (void)n_in; (void)out_size; (void)ws_size;
  const float* masks  = (const float*)d_in[0];
  const float* bf     = (const float*)d_in[1];
  const float* seq    = (const float*)d_in[2];
  const float* cmid   = (const float*)d_in[3];
  const float* clow   = (const float*)d_in[4];
  const int*   length = (const int*)d_in[5];
  const int*   iter   = (const int*)d_in[6];
  const float* alpha  = (const float*)d_in[7];
  float* out = (float*)d_out;

  float* perb = (float*)d_ws;   // 512*8 f32; indices 0-6 fully written every launch

  float* out_mask = out + 4;
  float* out_smid = out + 4 + 3538944;
  float* out_slow = out + 4 + 3538944 + 13631488;

  k_mega<<<NB, 1024, 0, stream>>>(masks, bf, seq, cmid, clow, length, alpha,
                                  out_mask, out_smid, out_slow, perb);
  k_final<<<1, 512, 0, stream>>>(perb, iter, out);
}